// Round 8
// baseline (31.148 us; speedup 1.0000x reference)
//
#include <hip/hip_runtime.h>

#define B_   16
#define T_   10
#define D_   256
#define MI_  32
#define MO_  16
#define RES_ 200
#define TWO_PI 6.28318530717958647692f

#define HSLICE 32
#define NHS    (D_ / HSLICE)              // 8
#define VPAD   68
#define BT_STRIDE (2 * MO_ * D_)          // 8192 floats: [C planes][S planes]
#define NSLOT  101                        // mirror slots 0..100
#define TRIG_OFF ((size_t)B_ * T_ * BT_STRIDE)          // float offset in ws
#define TRIG_FLOATS (NSLOT * 2 * MO_)                   // 3232
#define TRIG_BLOCKS 7                                   // 7*256 >= 1616 pairs
#define WS_FLOATS (TRIG_OFF + TRIG_FLOATS)

using f32x4 = __attribute__((ext_vector_type(4))) float;

// ---------- Kernel A: contraction -> ws [bt][{C,S}][o][h]; + trig table ----
// grid 1287 = bt(160) x hs(8) + 7 trig blocks; block 256 = og(8) x h_l(32).
__global__ __launch_bounds__(256) void spectral_cs(
    const float* __restrict__ v,
    const float* __restrict__ w_real,
    const float* __restrict__ w_imag,
    float* __restrict__ ws)
{
    const int blk = blockIdx.x;

    if (blk >= B_ * T_ * NHS) {          // ---- trig-table builder blocks ----
        const int p = (blk - B_ * T_ * NHS) * 256 + threadIdx.x;  // pair idx
        if (p < NSLOT * MO_) {
            const int s = p >> 4;
            const int o = p & 15;
            const int k = (s * o) % RES_;
            float ang = TWO_PI * ((float)k * (1.0f / (float)RES_));
            float sv, cv;
            __sincosf(ang, &sv, &cv);
            float* tt = ws + TRIG_OFF;
            tt[2 * p]     = cv;
            tt[2 * p + 1] = sv;
        }
        return;
    }

    const int bt  = blk >> 3;
    const int hs  = blk & 7;
    const int t   = bt % T_;

    __shared__ float s_v[HSLICE * VPAD];     // 8.5 KB

    {   // cooperative v-slice stage (v read exactly once per element)
        const float4* gv = reinterpret_cast<const float4*>(
            v + ((size_t)bt * D_ + hs * HSLICE) * (2 * MI_));
        #pragma unroll
        for (int j = 0; j < 2; ++j) {
            const int f = threadIdx.x + 256 * j;
            const int h = f >> 4;
            const int m = (f & 15) * 4;
            *reinterpret_cast<float4*>(&s_v[h * VPAD + m]) = gv[f];
        }
    }
    __syncthreads();

    const int og  = threadIdx.x >> 5;
    const int h_l = threadIdx.x & 31;
    const int o0  = og * 2;
    const int h_g = hs * HSLICE + h_l;

    float rr[MI_], ii[MI_];
    #pragma unroll
    for (int j = 0; j < 8; ++j) {
        float4 q = *reinterpret_cast<const float4*>(&s_v[h_l * VPAD + 4 * j]);
        rr[4*j+0]=q.x; rr[4*j+1]=q.y; rr[4*j+2]=q.z; rr[4*j+3]=q.w;
    }
    #pragma unroll
    for (int j = 0; j < 8; ++j) {
        float4 q = *reinterpret_cast<const float4*>(&s_v[h_l * VPAD + 32 + 4 * j]);
        ii[4*j+0]=q.x; ii[4*j+1]=q.y; ii[4*j+2]=q.z; ii[4*j+3]=q.w;
    }

    const float* wrt = w_real + ((size_t)t * MO_ + o0) * MI_;
    const float* wit = w_imag + ((size_t)t * MO_ + o0) * MI_;

    float* wsb = ws + (size_t)bt * BT_STRIDE;
    #pragma unroll
    for (int ol = 0; ol < 2; ++ol) {
        const float4* wa = reinterpret_cast<const float4*>(wrt + ol * MI_);
        const float4* wb = reinterpret_cast<const float4*>(wit + ol * MI_);
        float c = 0.f, s = 0.f;
        #pragma unroll
        for (int mq = 0; mq < 8; ++mq) {
            float4 a4 = wa[mq];
            float4 b4 = wb[mq];
            c = fmaf(rr[4*mq+0], a4.x, c); c = fmaf(-ii[4*mq+0], b4.x, c);
            s = fmaf(rr[4*mq+0], b4.x, s); s = fmaf( ii[4*mq+0], a4.x, s);
            c = fmaf(rr[4*mq+1], a4.y, c); c = fmaf(-ii[4*mq+1], b4.y, c);
            s = fmaf(rr[4*mq+1], b4.y, s); s = fmaf( ii[4*mq+1], a4.y, s);
            c = fmaf(rr[4*mq+2], a4.z, c); c = fmaf(-ii[4*mq+2], b4.z, c);
            s = fmaf(rr[4*mq+2], b4.z, s); s = fmaf( ii[4*mq+2], a4.z, s);
            c = fmaf(rr[4*mq+3], a4.w, c); c = fmaf(-ii[4*mq+3], b4.w, c);
            s = fmaf(rr[4*mq+3], b4.w, s); s = fmaf( ii[4*mq+3], a4.w, s);
        }
        const int o = o0 + ol;
        wsb[o * D_ + h_g]            = c;   // C plane (L2-resident for B)
        wsb[MO_ * D_ + o * D_ + h_g] = s;   // S plane
    }
}

// ---------- Kernel B: row-wave IFT, table-driven, 1KB wave stores ----------
// grid 1280 = bt(160) x qb(8); block 256 = 4 waves; wave = full output row.
// lane owns h = 4*lane..4*lane+3; slots s = g + 32k (g = wave idx in bt).
__global__ __launch_bounds__(256) void spectral_ift(
    const float* __restrict__ ws,
    float* __restrict__ out)
{
    const int blk  = blockIdx.x;
    const int bt   = blk >> 3;
    const int qb   = blk & 7;
    const int wave = threadIdx.x >> 6;
    const int lane = threadIdx.x & 63;
    const int g    = qb * 4 + wave;      // 0..31
    const int h0   = lane * 4;

    __shared__ float s_tt[TRIG_FLOATS];  // 12.9 KB: [slot][o] -> (cos,sin)

    // stage trig table (global, L2-hot) -> LDS
    {
        const float4* gt4 = reinterpret_cast<const float4*>(ws + TRIG_OFF);
        #pragma unroll
        for (int i = 0; i < 4; ++i) {
            const int idx = threadIdx.x + 256 * i;
            if (idx < TRIG_FLOATS / 4)
                reinterpret_cast<float4*>(s_tt)[idx] = gt4[idx];
        }
    }

    // C,S for this lane's 4 h into registers (issue before the barrier)
    const float* wsb = ws + (size_t)bt * BT_STRIDE;
    float C[MO_][4], S[MO_][4];
    #pragma unroll
    for (int o = 0; o < MO_; ++o) {
        float4 c4 = *reinterpret_cast<const float4*>(&wsb[o * D_ + h0]);
        float4 s4 = *reinterpret_cast<const float4*>(&wsb[MO_ * D_ + o * D_ + h0]);
        C[o][0]=c4.x; C[o][1]=c4.y; C[o][2]=c4.z; C[o][3]=c4.w;
        S[o][0]=s4.x; S[o][1]=s4.y; S[o][2]=s4.z; S[o][3]=s4.w;
    }
    __syncthreads();

    float* ob = out + (size_t)bt * RES_ * D_;

    #pragma unroll
    for (int k = 0; k < 4; ++k) {
        const int s = g + 32 * k;        // wave-uniform slot
        if (s <= 100) {
            const float* tp = &s_tt[s * 2 * MO_];
            float a0=0.f,a1=0.f,a2=0.f,a3=0.f;
            float b0=0.f,b1=0.f,b2=0.f,b3=0.f;
            #pragma unroll
            for (int o = 0; o < MO_; ++o) {
                float2 tv = *reinterpret_cast<const float2*>(&tp[2 * o]);
                a0 = fmaf(C[o][0], tv.x, a0);
                a1 = fmaf(C[o][1], tv.x, a1);
                a2 = fmaf(C[o][2], tv.x, a2);
                a3 = fmaf(C[o][3], tv.x, a3);
                b0 = fmaf(S[o][0], tv.y, b0);
                b1 = fmaf(S[o][1], tv.y, b1);
                b2 = fmaf(S[o][2], tv.y, b2);
                b3 = fmaf(S[o][3], tv.y, b3);
            }
            const int mr = (s == 0) ? 0 : (RES_ - s);
            f32x4 lo, hi;
            lo.x = a0 - b0; lo.y = a1 - b1; lo.z = a2 - b2; lo.w = a3 - b3;
            hi.x = a0 + b0; hi.y = a1 + b1; hi.z = a2 + b2; hi.w = a3 + b3;
            // full-row wave store: 64 lanes x 16B = 1KB contiguous
            __builtin_nontemporal_store(
                lo, reinterpret_cast<f32x4*>(&ob[(size_t)s  * D_ + h0]));
            __builtin_nontemporal_store(
                hi, reinterpret_cast<f32x4*>(&ob[(size_t)mr * D_ + h0]));
        }
    }
}

extern "C" void kernel_launch(void* const* d_in, const int* in_sizes, int n_in,
                              void* d_out, int out_size, void* d_ws, size_t ws_size,
                              hipStream_t stream) {
    const float* v  = (const float*)d_in[0];
    const float* wr = (const float*)d_in[1];
    const float* wi = (const float*)d_in[2];
    float* out = (float*)d_out;
    float* ws  = (float*)d_ws;

    spectral_cs <<<B_ * T_ * NHS + TRIG_BLOCKS, 256, 0, stream>>>(v, wr, wi, ws);
    spectral_ift<<<B_ * T_ * 8,                 256, 0, stream>>>(ws, out);
}

// Round 9
// 29.812 us; speedup vs baseline: 1.0448x; 1.0448x over previous
//
#include <hip/hip_runtime.h>

#define B_   16
#define T_   10
#define D_   256
#define MI_  32
#define MO_  16
#define RES_ 200
#define TWO_PI 6.28318530717958647692f

#define HSLICE 32
#define NHS    (D_ / NHS_DIV)
#define NHS_DIV HSLICE
#undef NHS
#define NHS    (D_ / HSLICE)              // 8
#define VPAD   68
#define BT_STRIDE (2 * MO_ * D_)          // 8192 floats: [C planes][S planes]

using f32x4 = __attribute__((ext_vector_type(4))) float;

// ---------- Kernel A: contraction -> ws [bt][{C,S}][o][h] ------------------
// grid 1280 = bt(160) x hs(8); block 256 = og(8) x h_l(32).  (round-7 proven)
__global__ __launch_bounds__(256) void spectral_cs(
    const float* __restrict__ v,
    const float* __restrict__ w_real,
    const float* __restrict__ w_imag,
    float* __restrict__ ws)
{
    const int blk = blockIdx.x;
    const int bt  = blk >> 3;
    const int hs  = blk & 7;
    const int t   = bt % T_;

    __shared__ float s_v[HSLICE * VPAD];     // 8.5 KB

    {   // cooperative v-slice stage (v read exactly once per element)
        const float4* gv = reinterpret_cast<const float4*>(
            v + ((size_t)bt * D_ + hs * HSLICE) * (2 * MI_));
        #pragma unroll
        for (int j = 0; j < 2; ++j) {
            const int f = threadIdx.x + 256 * j;
            const int h = f >> 4;
            const int m = (f & 15) * 4;
            *reinterpret_cast<float4*>(&s_v[h * VPAD + m]) = gv[f];
        }
    }
    __syncthreads();

    const int og  = threadIdx.x >> 5;
    const int h_l = threadIdx.x & 31;
    const int o0  = og * 2;
    const int h_g = hs * HSLICE + h_l;

    float rr[MI_], ii[MI_];
    #pragma unroll
    for (int j = 0; j < 8; ++j) {
        float4 q = *reinterpret_cast<const float4*>(&s_v[h_l * VPAD + 4 * j]);
        rr[4*j+0]=q.x; rr[4*j+1]=q.y; rr[4*j+2]=q.z; rr[4*j+3]=q.w;
    }
    #pragma unroll
    for (int j = 0; j < 8; ++j) {
        float4 q = *reinterpret_cast<const float4*>(&s_v[h_l * VPAD + 32 + 4 * j]);
        ii[4*j+0]=q.x; ii[4*j+1]=q.y; ii[4*j+2]=q.z; ii[4*j+3]=q.w;
    }

    const float* wrt = w_real + ((size_t)t * MO_ + o0) * MI_;
    const float* wit = w_imag + ((size_t)t * MO_ + o0) * MI_;

    float* wsb = ws + (size_t)bt * BT_STRIDE;
    #pragma unroll
    for (int ol = 0; ol < 2; ++ol) {
        const float4* wa = reinterpret_cast<const float4*>(wrt + ol * MI_);
        const float4* wb = reinterpret_cast<const float4*>(wit + ol * MI_);
        float c = 0.f, s = 0.f;
        #pragma unroll
        for (int mq = 0; mq < 8; ++mq) {
            float4 a4 = wa[mq];
            float4 b4 = wb[mq];
            c = fmaf(rr[4*mq+0], a4.x, c); c = fmaf(-ii[4*mq+0], b4.x, c);
            s = fmaf(rr[4*mq+0], b4.x, s); s = fmaf( ii[4*mq+0], a4.x, s);
            c = fmaf(rr[4*mq+1], a4.y, c); c = fmaf(-ii[4*mq+1], b4.y, c);
            s = fmaf(rr[4*mq+1], b4.y, s); s = fmaf( ii[4*mq+1], a4.y, s);
            c = fmaf(rr[4*mq+2], a4.z, c); c = fmaf(-ii[4*mq+2], b4.z, c);
            s = fmaf(rr[4*mq+2], b4.z, s); s = fmaf( ii[4*mq+2], a4.z, s);
            c = fmaf(rr[4*mq+3], a4.w, c); c = fmaf(-ii[4*mq+3], b4.w, c);
            s = fmaf(rr[4*mq+3], b4.w, s); s = fmaf( ii[4*mq+3], a4.w, s);
        }
        const int o = o0 + ol;
        wsb[o * D_ + h_g]            = c;   // C plane (L2-resident for B)
        wsb[MO_ * D_ + o * D_ + h_g] = s;   // S plane
    }
}

// ---------- Kernel B: row-wave IFT, rotation trig, 1KB wave stores ---------
// grid 1280 = bt(160) x sq(8); block 256 = 4 waves; wave = full output row.
// lane owns h = 4*lane..4*lane+3; wave g = sq*4+w in 0..31; slots s = g+32k.
__global__ __launch_bounds__(256) void spectral_ift(
    const float* __restrict__ ws,
    float* __restrict__ out)
{
    const int blk  = blockIdx.x;
    const int bt   = blk >> 3;
    const int sq   = blk & 7;
    const int wave = threadIdx.x >> 6;
    const int lane = threadIdx.x & 63;
    const int g    = sq * 4 + wave;      // 0..31
    const int h0   = lane * 4;

    const float* wsb = ws + (size_t)bt * BT_STRIDE;
    float C[MO_][4], S[MO_][4];
    #pragma unroll
    for (int o = 0; o < MO_; ++o) {
        float4 c4 = *reinterpret_cast<const float4*>(&wsb[o * D_ + h0]);
        float4 s4 = *reinterpret_cast<const float4*>(&wsb[MO_ * D_ + o * D_ + h0]);
        C[o][0]=c4.x; C[o][1]=c4.y; C[o][2]=c4.z; C[o][3]=c4.w;
        S[o][0]=s4.x; S[o][1]=s4.y; S[o][2]=s4.z; S[o][3]=s4.w;
    }

    float* ob = out + (size_t)bt * RES_ * D_;

    #pragma unroll
    for (int k = 0; k < 4; ++k) {
        const int s = g + 32 * k;        // wave-uniform slot
        if (s <= 100) {
            const float phi = (float)s * (TWO_PI / (float)RES_);
            float s1, c1;
            __sincosf(phi, &s1, &c1);

            float a0=0.f,a1=0.f,a2=0.f,a3=0.f;
            float b0=0.f,b1=0.f,b2=0.f,b3=0.f;
            float co = 1.f, so = 0.f;
            #pragma unroll
            for (int o = 0; o < MO_; ++o) {
                a0 = fmaf(C[o][0], co, a0);
                a1 = fmaf(C[o][1], co, a1);
                a2 = fmaf(C[o][2], co, a2);
                a3 = fmaf(C[o][3], co, a3);
                b0 = fmaf(S[o][0], so, b0);
                b1 = fmaf(S[o][1], so, b1);
                b2 = fmaf(S[o][2], so, b2);
                b3 = fmaf(S[o][3], so, b3);
                const float nc = fmaf(co, c1, -(so * s1));
                const float ns = fmaf(so, c1,  (co * s1));
                co = nc; so = ns;
            }

            const int mr = (s == 0) ? 0 : (RES_ - s);
            f32x4 lo, hi;
            lo.x = a0 - b0; lo.y = a1 - b1; lo.z = a2 - b2; lo.w = a3 - b3;
            hi.x = a0 + b0; hi.y = a1 + b1; hi.z = a2 + b2; hi.w = a3 + b3;
            // full-row wave store: 64 lanes x 16B = 1KB contiguous
            __builtin_nontemporal_store(
                lo, reinterpret_cast<f32x4*>(&ob[(size_t)s  * D_ + h0]));
            __builtin_nontemporal_store(
                hi, reinterpret_cast<f32x4*>(&ob[(size_t)mr * D_ + h0]));
        }
    }
}

extern "C" void kernel_launch(void* const* d_in, const int* in_sizes, int n_in,
                              void* d_out, int out_size, void* d_ws, size_t ws_size,
                              hipStream_t stream) {
    const float* v  = (const float*)d_in[0];
    const float* wr = (const float*)d_in[1];
    const float* wi = (const float*)d_in[2];
    float* out = (float*)d_out;
    float* ws  = (float*)d_ws;

    spectral_cs <<<B_ * T_ * NHS, 256, 0, stream>>>(v, wr, wi, ws);
    spectral_ift<<<B_ * T_ * 8,   256, 0, stream>>>(ws, out);
}

// Round 10
// 24.987 us; speedup vs baseline: 1.2466x; 1.1931x over previous
//
#include <hip/hip_runtime.h>

#define B_   16
#define T_   10
#define D_   256
#define MI_  32
#define MO_  16
#define RES_ 200
#define TWO_PI 6.28318530717958647692f

#define HSLICE 32
#define NHS    (D_ / HSLICE)              // 8
#define VPAD   68
#define BT_STRIDE (2 * MO_ * D_)          // 8192 floats: [o][h] -> (C,S) pairs

using f32x4 = __attribute__((ext_vector_type(4))) float;
using v2f   = __attribute__((ext_vector_type(2))) float;

// ---------- Kernel A: contraction -> ws[bt][o][h] = (C,S) interleaved ------
// grid 1280 = bt(160) x hs(8); block 256 = og(8) x h_l(32).
__global__ __launch_bounds__(256) void spectral_cs(
    const float* __restrict__ v,
    const float* __restrict__ w_real,
    const float* __restrict__ w_imag,
    float* __restrict__ ws)
{
    const int blk = blockIdx.x;
    const int bt  = blk >> 3;
    const int hs  = blk & 7;
    const int t   = bt % T_;

    __shared__ float s_v[HSLICE * VPAD];     // 8.5 KB

    {   // cooperative v-slice stage (v read exactly once per element)
        const float4* gv = reinterpret_cast<const float4*>(
            v + ((size_t)bt * D_ + hs * HSLICE) * (2 * MI_));
        #pragma unroll
        for (int j = 0; j < 2; ++j) {
            const int f = threadIdx.x + 256 * j;
            const int h = f >> 4;
            const int m = (f & 15) * 4;
            *reinterpret_cast<float4*>(&s_v[h * VPAD + m]) = gv[f];
        }
    }
    __syncthreads();

    const int og  = threadIdx.x >> 5;
    const int h_l = threadIdx.x & 31;
    const int o0  = og * 2;
    const int h_g = hs * HSLICE + h_l;

    float rr[MI_], ii[MI_];
    #pragma unroll
    for (int j = 0; j < 8; ++j) {
        float4 q = *reinterpret_cast<const float4*>(&s_v[h_l * VPAD + 4 * j]);
        rr[4*j+0]=q.x; rr[4*j+1]=q.y; rr[4*j+2]=q.z; rr[4*j+3]=q.w;
    }
    #pragma unroll
    for (int j = 0; j < 8; ++j) {
        float4 q = *reinterpret_cast<const float4*>(&s_v[h_l * VPAD + 32 + 4 * j]);
        ii[4*j+0]=q.x; ii[4*j+1]=q.y; ii[4*j+2]=q.z; ii[4*j+3]=q.w;
    }

    const float* wrt = w_real + ((size_t)t * MO_ + o0) * MI_;
    const float* wit = w_imag + ((size_t)t * MO_ + o0) * MI_;

    float* wsb = ws + (size_t)bt * BT_STRIDE;
    #pragma unroll
    for (int ol = 0; ol < 2; ++ol) {
        const float4* wa = reinterpret_cast<const float4*>(wrt + ol * MI_);
        const float4* wb = reinterpret_cast<const float4*>(wit + ol * MI_);
        float c = 0.f, s = 0.f;
        #pragma unroll
        for (int mq = 0; mq < 8; ++mq) {
            float4 a4 = wa[mq];
            float4 b4 = wb[mq];
            c = fmaf(rr[4*mq+0], a4.x, c); c = fmaf(-ii[4*mq+0], b4.x, c);
            s = fmaf(rr[4*mq+0], b4.x, s); s = fmaf( ii[4*mq+0], a4.x, s);
            c = fmaf(rr[4*mq+1], a4.y, c); c = fmaf(-ii[4*mq+1], b4.y, c);
            s = fmaf(rr[4*mq+1], b4.y, s); s = fmaf( ii[4*mq+1], a4.y, s);
            c = fmaf(rr[4*mq+2], a4.z, c); c = fmaf(-ii[4*mq+2], b4.z, c);
            s = fmaf(rr[4*mq+2], b4.z, s); s = fmaf( ii[4*mq+2], a4.z, s);
            c = fmaf(rr[4*mq+3], a4.w, c); c = fmaf(-ii[4*mq+3], b4.w, c);
            s = fmaf(rr[4*mq+3], b4.w, s); s = fmaf( ii[4*mq+3], a4.w, s);
        }
        const int o = o0 + ol;
        v2f p; p.x = c; p.y = s;
        // interleaved pair store: 32 lanes x 8B = 256B contiguous run
        *reinterpret_cast<v2f*>(&wsb[2 * (o * D_ + h_g)]) = p;
    }
}

// ---------- Kernel B: row-wave IFT, packed pk_fma accumulation -------------
// grid 640 = bt(160) x qb(4); block 256 = 4 waves; wave = full output row.
// lane owns h = 4*lane..4*lane+3; slots s = g + 16k (g = wave idx in bt).
// Pair accumulator per h: ab_h = sum_o (C[o],S[o]) * (cos,sin)  [v_pk_fma_f32]
__global__ __launch_bounds__(256) void spectral_ift(
    const float* __restrict__ ws,
    float* __restrict__ out)
{
    const int blk  = blockIdx.x;
    const int bt   = blk >> 2;
    const int qb   = blk & 3;
    const int wave = threadIdx.x >> 6;
    const int lane = threadIdx.x & 63;
    const int g    = qb * 4 + wave;      // 0..15
    const int h0   = lane * 4;

    const float* wsb = ws + (size_t)bt * BT_STRIDE;
    v2f CS0[MO_], CS1[MO_], CS2[MO_], CS3[MO_];
    #pragma unroll
    for (int o = 0; o < MO_; ++o) {
        float4 q0 = *reinterpret_cast<const float4*>(&wsb[2 * (o * D_ + h0)]);
        float4 q1 = *reinterpret_cast<const float4*>(&wsb[2 * (o * D_ + h0) + 4]);
        CS0[o].x = q0.x; CS0[o].y = q0.y;
        CS1[o].x = q0.z; CS1[o].y = q0.w;
        CS2[o].x = q1.x; CS2[o].y = q1.y;
        CS3[o].x = q1.z; CS3[o].y = q1.w;
    }

    float* ob = out + (size_t)bt * RES_ * D_;

    #pragma unroll
    for (int k = 0; k < 7; ++k) {
        const int s = g + 16 * k;        // wave-uniform slot
        if (s <= 100) {
            const float phi = (float)s * (TWO_PI / (float)RES_);
            float s1, c1;
            __sincosf(phi, &s1, &c1);

            v2f ab0 = {0.f, 0.f}, ab1 = {0.f, 0.f};
            v2f ab2 = {0.f, 0.f}, ab3 = {0.f, 0.f};
            v2f cs;  cs.x = 1.f; cs.y = 0.f;      // (cos(o*phi), sin(o*phi))
            #pragma unroll
            for (int o = 0; o < MO_; ++o) {
                ab0 = __builtin_elementwise_fma(CS0[o], cs, ab0);
                ab1 = __builtin_elementwise_fma(CS1[o], cs, ab1);
                ab2 = __builtin_elementwise_fma(CS2[o], cs, ab2);
                ab3 = __builtin_elementwise_fma(CS3[o], cs, ab3);
                const float nc = fmaf(cs.x, c1, -(cs.y * s1));
                const float ns = fmaf(cs.y, c1,  (cs.x * s1));
                cs.x = nc; cs.y = ns;
            }

            const int mr = (s == 0) ? 0 : (RES_ - s);
            f32x4 lo, hi;
            lo.x = ab0.x - ab0.y; hi.x = ab0.x + ab0.y;
            lo.y = ab1.x - ab1.y; hi.y = ab1.x + ab1.y;
            lo.z = ab2.x - ab2.y; hi.z = ab2.x + ab2.y;
            lo.w = ab3.x - ab3.y; hi.w = ab3.x + ab3.y;
            // full-row wave store: 64 lanes x 16B = 1KB contiguous
            __builtin_nontemporal_store(
                lo, reinterpret_cast<f32x4*>(&ob[(size_t)s  * D_ + h0]));
            __builtin_nontemporal_store(
                hi, reinterpret_cast<f32x4*>(&ob[(size_t)mr * D_ + h0]));
        }
    }
}

extern "C" void kernel_launch(void* const* d_in, const int* in_sizes, int n_in,
                              void* d_out, int out_size, void* d_ws, size_t ws_size,
                              hipStream_t stream) {
    const float* v  = (const float*)d_in[0];
    const float* wr = (const float*)d_in[1];
    const float* wi = (const float*)d_in[2];
    float* out = (float*)d_out;
    float* ws  = (float*)d_ws;

    spectral_cs <<<B_ * T_ * NHS, 256, 0, stream>>>(v, wr, wi, ws);
    spectral_ift<<<B_ * T_ * 4,   256, 0, stream>>>(ws, out);
}

// Round 11
// 21.649 us; speedup vs baseline: 1.4388x; 1.1542x over previous
//
#include <hip/hip_runtime.h>

#define B_   16
#define T_   10
#define D_   256
#define MI_  32
#define MO_  16
#define RES_ 200
#define TWO_PI 6.28318530717958647692f

#define HSLICE 32
#define NHS    (D_ / HSLICE)              // 8
#define VPAD   68
#define BT_STRIDE (2 * MO_ * D_)          // 8192 floats: [o][h] -> (C,S) pairs

using f32x4 = __attribute__((ext_vector_type(4))) float;
using v2f   = __attribute__((ext_vector_type(2))) float;

// ---------- Kernel A: contraction -> ws[bt][o][h] = (C,S) interleaved ------
// grid 1280; XCD-aligned: blk = (bt&7) + 8*((bt>>3)*8 + hs)  ->  blk%8 = bt%8
__global__ __launch_bounds__(256) void spectral_cs(
    const float* __restrict__ v,
    const float* __restrict__ w_real,
    const float* __restrict__ w_imag,
    float* __restrict__ ws)
{
    const int a    = blockIdx.x;
    const int r    = a & 7;
    const int rest = a >> 3;           // 0..159
    const int hs   = rest & 7;
    const int q    = rest >> 3;        // 0..19
    const int bt   = 8 * q + r;
    const int t    = bt % T_;

    __shared__ float s_v[HSLICE * VPAD];     // 8.5 KB

    {   // cooperative v-slice stage (v read exactly once per element)
        const float4* gv = reinterpret_cast<const float4*>(
            v + ((size_t)bt * D_ + hs * HSLICE) * (2 * MI_));
        #pragma unroll
        for (int j = 0; j < 2; ++j) {
            const int f = threadIdx.x + 256 * j;
            const int h = f >> 4;
            const int m = (f & 15) * 4;
            *reinterpret_cast<float4*>(&s_v[h * VPAD + m]) = gv[f];
        }
    }
    __syncthreads();

    const int og  = threadIdx.x >> 5;
    const int h_l = threadIdx.x & 31;
    const int o0  = og * 2;
    const int h_g = hs * HSLICE + h_l;

    float rr[MI_], ii[MI_];
    #pragma unroll
    for (int j = 0; j < 8; ++j) {
        float4 q4 = *reinterpret_cast<const float4*>(&s_v[h_l * VPAD + 4 * j]);
        rr[4*j+0]=q4.x; rr[4*j+1]=q4.y; rr[4*j+2]=q4.z; rr[4*j+3]=q4.w;
    }
    #pragma unroll
    for (int j = 0; j < 8; ++j) {
        float4 q4 = *reinterpret_cast<const float4*>(&s_v[h_l * VPAD + 32 + 4 * j]);
        ii[4*j+0]=q4.x; ii[4*j+1]=q4.y; ii[4*j+2]=q4.z; ii[4*j+3]=q4.w;
    }

    const float* wrt = w_real + ((size_t)t * MO_ + o0) * MI_;
    const float* wit = w_imag + ((size_t)t * MO_ + o0) * MI_;

    float* wsb = ws + (size_t)bt * BT_STRIDE;
    #pragma unroll
    for (int ol = 0; ol < 2; ++ol) {
        const float4* wa = reinterpret_cast<const float4*>(wrt + ol * MI_);
        const float4* wb = reinterpret_cast<const float4*>(wit + ol * MI_);
        float c = 0.f, s = 0.f;
        #pragma unroll
        for (int mq = 0; mq < 8; ++mq) {
            float4 a4 = wa[mq];
            float4 b4 = wb[mq];
            c = fmaf(rr[4*mq+0], a4.x, c); c = fmaf(-ii[4*mq+0], b4.x, c);
            s = fmaf(rr[4*mq+0], b4.x, s); s = fmaf( ii[4*mq+0], a4.x, s);
            c = fmaf(rr[4*mq+1], a4.y, c); c = fmaf(-ii[4*mq+1], b4.y, c);
            s = fmaf(rr[4*mq+1], b4.y, s); s = fmaf( ii[4*mq+1], a4.y, s);
            c = fmaf(rr[4*mq+2], a4.z, c); c = fmaf(-ii[4*mq+2], b4.z, c);
            s = fmaf(rr[4*mq+2], b4.z, s); s = fmaf( ii[4*mq+2], a4.z, s);
            c = fmaf(rr[4*mq+3], a4.w, c); c = fmaf(-ii[4*mq+3], b4.w, c);
            s = fmaf(rr[4*mq+3], b4.w, s); s = fmaf( ii[4*mq+3], a4.w, s);
        }
        const int o = o0 + ol;
        v2f p; p.x = c; p.y = s;
        // interleaved pair store: 32 lanes x 8B = 256B contiguous run
        *reinterpret_cast<v2f*>(&wsb[2 * (o * D_ + h_g)]) = p;
    }
}

// ---------- Kernel B: row-wave IFT, LDS-staged CS, pk_fma, 1KB stores ------
// grid 640; XCD-aligned: blk = (bt&7) + 8*((bt>>3)*4 + qb)  ->  blk%8 = bt%8
// block 256 = 4 waves; wave = full output row; lane owns h = 4*lane..4*lane+3.
__global__ __launch_bounds__(256) void spectral_ift(
    const float* __restrict__ ws,
    float* __restrict__ out)
{
    const int b    = blockIdx.x;
    const int r    = b & 7;
    const int rest = b >> 3;           // 0..79
    const int qb   = rest & 3;
    const int q    = rest >> 2;        // 0..19
    const int bt   = 8 * q + r;
    const int wave = threadIdx.x >> 6;
    const int lane = threadIdx.x & 63;
    const int g    = qb * 4 + wave;    // 0..15
    const int h0   = lane * 4;

    __shared__ float s_cs[BT_STRIDE];  // 32 KB: full bt C,S pairs [o][h]

    {   // cooperative stage: 32 KB, coalesced, read ONCE per block (L2-local)
        const float4* g4 = reinterpret_cast<const float4*>(
            ws + (size_t)bt * BT_STRIDE);
        float4* s4 = reinterpret_cast<float4*>(s_cs);
        #pragma unroll
        for (int i = 0; i < 8; ++i)
            s4[threadIdx.x + 256 * i] = g4[threadIdx.x + 256 * i];
    }
    __syncthreads();

    // per-lane C,S registers from LDS (b128, full-BW pattern)
    v2f CS0[MO_], CS1[MO_], CS2[MO_], CS3[MO_];
    #pragma unroll
    for (int o = 0; o < MO_; ++o) {
        float4 q0 = *reinterpret_cast<const float4*>(&s_cs[2 * (o * D_ + h0)]);
        float4 q1 = *reinterpret_cast<const float4*>(&s_cs[2 * (o * D_ + h0) + 4]);
        CS0[o].x = q0.x; CS0[o].y = q0.y;
        CS1[o].x = q0.z; CS1[o].y = q0.w;
        CS2[o].x = q1.x; CS2[o].y = q1.y;
        CS3[o].x = q1.z; CS3[o].y = q1.w;
    }

    float* ob = out + (size_t)bt * RES_ * D_;

    #pragma unroll
    for (int k = 0; k < 7; ++k) {
        const int s = g + 16 * k;        // wave-uniform slot
        if (s <= 100) {
            const float phi = (float)s * (TWO_PI / (float)RES_);
            float s1, c1;
            __sincosf(phi, &s1, &c1);

            v2f ab0 = {0.f, 0.f}, ab1 = {0.f, 0.f};
            v2f ab2 = {0.f, 0.f}, ab3 = {0.f, 0.f};
            v2f cs;  cs.x = 1.f; cs.y = 0.f;      // (cos(o*phi), sin(o*phi))
            #pragma unroll
            for (int o = 0; o < MO_; ++o) {
                ab0 = __builtin_elementwise_fma(CS0[o], cs, ab0);
                ab1 = __builtin_elementwise_fma(CS1[o], cs, ab1);
                ab2 = __builtin_elementwise_fma(CS2[o], cs, ab2);
                ab3 = __builtin_elementwise_fma(CS3[o], cs, ab3);
                const float nc = fmaf(cs.x, c1, -(cs.y * s1));
                const float ns = fmaf(cs.y, c1,  (cs.x * s1));
                cs.x = nc; cs.y = ns;
            }

            const int mr = (s == 0) ? 0 : (RES_ - s);
            f32x4 lo, hi;
            lo.x = ab0.x - ab0.y; hi.x = ab0.x + ab0.y;
            lo.y = ab1.x - ab1.y; hi.y = ab1.x + ab1.y;
            lo.z = ab2.x - ab2.y; hi.z = ab2.x + ab2.y;
            lo.w = ab3.x - ab3.y; hi.w = ab3.x + ab3.y;
            // full-row wave store: 64 lanes x 16B = 1KB contiguous
            __builtin_nontemporal_store(
                lo, reinterpret_cast<f32x4*>(&ob[(size_t)s  * D_ + h0]));
            __builtin_nontemporal_store(
                hi, reinterpret_cast<f32x4*>(&ob[(size_t)mr * D_ + h0]));
        }
    }
}

extern "C" void kernel_launch(void* const* d_in, const int* in_sizes, int n_in,
                              void* d_out, int out_size, void* d_ws, size_t ws_size,
                              hipStream_t stream) {
    const float* v  = (const float*)d_in[0];
    const float* wr = (const float*)d_in[1];
    const float* wi = (const float*)d_in[2];
    float* out = (float*)d_out;
    float* ws  = (float*)d_ws;

    spectral_cs <<<B_ * T_ * NHS, 256, 0, stream>>>(v, wr, wi, ws);
    spectral_ift<<<B_ * T_ * 4,   256, 0, stream>>>(ws, out);
}